// Round 1
// baseline (231.757 us; speedup 1.0000x reference)
//
#include <hip/hip_runtime.h>
#include <hip/hip_bf16.h>

// Problem constants: B=2, S=2048, D=1024, H=16, Hd=64
// Pipeline: cvt(x,w_qkv,w_proj) -> QKV GEMM(bf16 MFMA, fp32 out+bias)
//           -> per-head LN (q scaled by 0.125) -> flash attention (bf16 MFMA)
//           -> proj GEMM -> fp32 out.

typedef __attribute__((ext_vector_type(8))) short bf16x8;  // 8 bf16 (4 VGPRs)
typedef __attribute__((ext_vector_type(4))) float f32x4;   // MFMA C/D frag

__device__ __forceinline__ unsigned short f2bf(float f) {
  union { float f; unsigned u; } v; v.f = f;
  unsigned r = v.u + 0x7FFFu + ((v.u >> 16) & 1u);   // round-to-nearest-even
  return (unsigned short)(r >> 16);
}

// ---------------- fp32 -> bf16 convert (vectorized) ----------------
__global__ __launch_bounds__(256) void k_cvt(const float* __restrict__ s,
                                             unsigned short* __restrict__ d,
                                             int n4) {
  int i = blockIdx.x * 256 + threadIdx.x;
  if (i >= n4) return;
  float4 v = ((const float4*)s)[i];
  ushort4 o;
  o.x = f2bf(v.x); o.y = f2bf(v.y); o.z = f2bf(v.z); o.w = f2bf(v.w);
  ((ushort4*)d)[i] = o;
}

// ---------------- NT bf16 GEMM: C[M][N] = A[M][K] * B[N][K]^T + bias ----------------
// 128x128 tile, BK=64, 256 threads (2x2 waves of 64x64), padded LDS rows (72)
__global__ __launch_bounds__(256) void k_gemm_nt(
    const unsigned short* __restrict__ A,   // [M][K] bf16
    const unsigned short* __restrict__ B,   // [N][K] bf16 (torch weight layout)
    const float* __restrict__ bias,         // [N]
    float* __restrict__ C,                  // [M][N] fp32
    int M, int N, int K)
{
  __shared__ unsigned short lA[128 * 72];
  __shared__ unsigned short lB[128 * 72];

  int tid = threadIdx.x;
  int lane = tid & 63, wid = tid >> 6;
  int lg = lane >> 4, lo = lane & 15;
  int wm = wid >> 1, wn = wid & 1;
  int m0 = blockIdx.y * 128, n0 = blockIdx.x * 128;

  f32x4 acc[4][4];
#pragma unroll
  for (int i = 0; i < 4; ++i)
#pragma unroll
    for (int j = 0; j < 4; ++j) acc[i][j] = (f32x4){0.f, 0.f, 0.f, 0.f};

  for (int kt = 0; kt < K; kt += 64) {
    __syncthreads();   // previous compute done before overwrite
    // stage A,B tiles: 128 rows x 64 k (8 chunks of 8 bf16); 1024 chunks / 256 thr
#pragma unroll
    for (int mth = 0; mth < 4; ++mth) {
      int cid = tid + 256 * mth;          // 0..1023
      int row = cid >> 3, c = cid & 7;
      bf16x8 av = *(const bf16x8*)(A + (size_t)(m0 + row) * K + kt + c * 8);
      *(bf16x8*)&lA[row * 72 + c * 8] = av;
      bf16x8 bv = *(const bf16x8*)(B + (size_t)(n0 + row) * K + kt + c * 8);
      *(bf16x8*)&lB[row * 72 + c * 8] = bv;
    }
    __syncthreads();

#pragma unroll
    for (int ks = 0; ks < 2; ++ks) {
      bf16x8 af[4], bfr[4];
#pragma unroll
      for (int i = 0; i < 4; ++i)
        af[i] = *(const bf16x8*)&lA[(wm * 64 + i * 16 + lo) * 72 + ks * 32 + lg * 8];
#pragma unroll
      for (int j = 0; j < 4; ++j)
        bfr[j] = *(const bf16x8*)&lB[(wn * 64 + j * 16 + lo) * 72 + ks * 32 + lg * 8];
#pragma unroll
      for (int i = 0; i < 4; ++i)
#pragma unroll
        for (int j = 0; j < 4; ++j)
          acc[i][j] = __builtin_amdgcn_mfma_f32_16x16x32_bf16(af[i], bfr[j], acc[i][j], 0, 0, 0);
    }
  }

  // epilogue: D[row=4*lg+r][col=lo] per 16x16 frag (verified m89/m91 mapping)
#pragma unroll
  for (int j = 0; j < 4; ++j) {
    int col = n0 + wn * 64 + j * 16 + lo;
    float bb = bias[col];
#pragma unroll
    for (int i = 0; i < 4; ++i) {
#pragma unroll
      for (int r = 0; r < 4; ++r) {
        int row = m0 + wm * 64 + i * 16 + lg * 4 + r;
        C[(size_t)row * N + col] = acc[i][j][r] + bb;
      }
    }
  }
}

// ---------------- per-head LayerNorm + layout transform ----------------
// one wave per (b,s,h): LN(q), LN(k) over Hd=64, copy v; outputs bf16 [B*H][S][64]
// q pre-scaled by 1/sqrt(64)=0.125
__global__ __launch_bounds__(256) void k_ln(
    const float* __restrict__ qkv,   // [B*S][3072]
    const float* __restrict__ qg, const float* __restrict__ qb,
    const float* __restrict__ kg, const float* __restrict__ kb,
    unsigned short* __restrict__ q, unsigned short* __restrict__ k,
    unsigned short* __restrict__ v)
{
  int wg = blockIdx.x * 4 + (threadIdx.x >> 6);
  int lane = threadIdx.x & 63;
  int h = wg & 15;
  int m = wg >> 4;                  // b*S + s
  const float* base = qkv + (size_t)m * 3072 + h * 64 + lane;
  float xq = base[0];
  float xk = base[1024];
  float xv = base[2048];

  float muq = xq, muk = xk;
#pragma unroll
  for (int t = 32; t; t >>= 1) { muq += __shfl_xor(muq, t, 64); muk += __shfl_xor(muk, t, 64); }
  muq *= (1.0f / 64.0f); muk *= (1.0f / 64.0f);
  float dq = xq - muq, dk = xk - muk;
  float vq = dq * dq, vk = dk * dk;
#pragma unroll
  for (int t = 32; t; t >>= 1) { vq += __shfl_xor(vq, t, 64); vk += __shfl_xor(vk, t, 64); }
  vq *= (1.0f / 64.0f); vk *= (1.0f / 64.0f);
  float yq = dq * rsqrtf(vq + 1e-5f) * qg[lane] + qb[lane];
  float yk = dk * rsqrtf(vk + 1e-5f) * kg[lane] + kb[lane];

  int b = m >> 11, s = m & 2047;
  size_t o = (((size_t)(b * 16 + h)) * 2048 + s) * 64 + lane;
  q[o] = f2bf(yq * 0.125f);
  k[o] = f2bf(yk);
  v[o] = f2bf(xv);
}

// ---------------- flash attention ----------------
// grid (S/64, B*H), 256 thr (4 waves x 16 q-rows). K, V^T staged in padded LDS;
// P re-shaped D-frag -> A-frag via wave-private LDS; online softmax fp32.
__global__ __launch_bounds__(256) void k_attn(
    const unsigned short* __restrict__ Q,   // [BH][S][64] bf16 (pre-scaled)
    const unsigned short* __restrict__ K,   // [BH][S][64]
    const unsigned short* __restrict__ V,   // [BH][S][64]
    unsigned short* __restrict__ O)         // [B*S][1024] bf16
{
  __shared__ unsigned short lK[64 * 72];
  __shared__ unsigned short lVT[64 * 72];
  __shared__ unsigned short lP[4][16 * 72];

  int tid = threadIdx.x;
  int wid = tid >> 6, lane = tid & 63, lg = lane >> 4, lo = lane & 15;
  int bh = blockIdx.y;
  int q0 = blockIdx.x * 64;

  // hoist Q fragments (A-frag: Q[lo][ks*32 + lg*8 + j])
  const unsigned short* qp = Q + ((size_t)bh * 2048 + q0 + wid * 16 + lo) * 64 + lg * 8;
  bf16x8 qf0 = *(const bf16x8*)qp;
  bf16x8 qf1 = *(const bf16x8*)(qp + 32);

  float mrun[4], lrun[4];
  f32x4 oacc[4];
#pragma unroll
  for (int r = 0; r < 4; ++r) { mrun[r] = -1e30f; lrun[r] = 0.0f; }
#pragma unroll
  for (int ct = 0; ct < 4; ++ct) oacc[ct] = (f32x4){0.f, 0.f, 0.f, 0.f};

  const unsigned short* kb0 = K + (size_t)bh * 2048 * 64;
  const unsigned short* vb0 = V + (size_t)bh * 2048 * 64;

  for (int kv0 = 0; kv0 < 2048; kv0 += 64) {
    __syncthreads();   // prior tile's reads done
    {
      int row = tid & 63;
      int c0 = tid >> 6;
#pragma unroll
      for (int cc = 0; cc < 2; ++cc) {
        int c = c0 + cc * 4;
        bf16x8 kk = *(const bf16x8*)(kb0 + ((size_t)(kv0 + row)) * 64 + c * 8);
        *(bf16x8*)&lK[row * 72 + c * 8] = kk;
        bf16x8 vv = *(const bf16x8*)(vb0 + ((size_t)(kv0 + row)) * 64 + c * 8);
#pragma unroll
        for (int j = 0; j < 8; ++j)
          lVT[(c * 8 + j) * 72 + row] = (unsigned short)vv[j];   // transpose for PV B-frags
      }
    }
    __syncthreads();

    // scores: S = Q @ K^T (pre-scaled); D row = q (4lg+r), col = kv (16ct+lo)
    f32x4 sc[4];
#pragma unroll
    for (int ct = 0; ct < 4; ++ct) sc[ct] = (f32x4){0.f, 0.f, 0.f, 0.f};
#pragma unroll
    for (int ct = 0; ct < 4; ++ct) {
      bf16x8 kf0 = *(const bf16x8*)&lK[(ct * 16 + lo) * 72 + lg * 8];
      sc[ct] = __builtin_amdgcn_mfma_f32_16x16x32_bf16(qf0, kf0, sc[ct], 0, 0, 0);
      bf16x8 kf1 = *(const bf16x8*)&lK[(ct * 16 + lo) * 72 + 32 + lg * 8];
      sc[ct] = __builtin_amdgcn_mfma_f32_16x16x32_bf16(qf1, kf1, sc[ct], 0, 0, 0);
    }

    // online softmax: per-row stats; row = 4lg+r lives on the 16 lanes sharing lg
    float pmax[4];
#pragma unroll
    for (int r = 0; r < 4; ++r)
      pmax[r] = fmaxf(fmaxf(sc[0][r], sc[1][r]), fmaxf(sc[2][r], sc[3][r]));
#pragma unroll
    for (int t = 8; t; t >>= 1)
#pragma unroll
      for (int r = 0; r < 4; ++r) pmax[r] = fmaxf(pmax[r], __shfl_xor(pmax[r], t, 64));

    float fac[4], psum[4];
#pragma unroll
    for (int r = 0; r < 4; ++r) {
      float mn = fmaxf(mrun[r], pmax[r]);
      fac[r] = __expf(mrun[r] - mn);   // -1e30 init avoids inf-inf NaN
      mrun[r] = mn;
      psum[r] = 0.f;
    }
#pragma unroll
    for (int ct = 0; ct < 4; ++ct)
#pragma unroll
      for (int r = 0; r < 4; ++r) {
        float pexp = __expf(sc[ct][r] - mrun[r]);
        sc[ct][r] = pexp;
        psum[r] += pexp;
      }
#pragma unroll
    for (int t = 8; t; t >>= 1)
#pragma unroll
      for (int r = 0; r < 4; ++r) psum[r] += __shfl_xor(psum[r], t, 64);
#pragma unroll
    for (int r = 0; r < 4; ++r) lrun[r] = lrun[r] * fac[r] + psum[r];
#pragma unroll
    for (int ct = 0; ct < 4; ++ct)
#pragma unroll
      for (int r = 0; r < 4; ++r) oacc[ct][r] *= fac[r];

    // P (D-frag layout) -> wave-private LDS -> A-frag layout
#pragma unroll
    for (int ct = 0; ct < 4; ++ct)
#pragma unroll
      for (int r = 0; r < 4; ++r)
        lP[wid][(lg * 4 + r) * 72 + ct * 16 + lo] = f2bf(sc[ct][r]);

    bf16x8 pf0 = *(const bf16x8*)&lP[wid][lo * 72 + lg * 8];
    bf16x8 pf1 = *(const bf16x8*)&lP[wid][lo * 72 + 32 + lg * 8];
#pragma unroll
    for (int ct = 0; ct < 4; ++ct) {
      bf16x8 vf0 = *(const bf16x8*)&lVT[(ct * 16 + lo) * 72 + lg * 8];
      oacc[ct] = __builtin_amdgcn_mfma_f32_16x16x32_bf16(pf0, vf0, oacc[ct], 0, 0, 0);
      bf16x8 vf1 = *(const bf16x8*)&lVT[(ct * 16 + lo) * 72 + 32 + lg * 8];
      oacc[ct] = __builtin_amdgcn_mfma_f32_16x16x32_bf16(pf1, vf1, oacc[ct], 0, 0, 0);
    }
  }

  // epilogue: O[(b*S + q)][h*64 + d] = oacc / lsum, bf16 for proj GEMM
  int b = bh >> 4, h = bh & 15;
#pragma unroll
  for (int ct = 0; ct < 4; ++ct) {
#pragma unroll
    for (int r = 0; r < 4; ++r) {
      int qrow = q0 + wid * 16 + lg * 4 + r;
      size_t off = ((size_t)(b * 2048 + qrow)) * 1024 + h * 64 + ct * 16 + lo;
      O[off] = f2bf(oacc[ct][r] / lrun[r]);
    }
  }
}

extern "C" void kernel_launch(void* const* d_in, const int* in_sizes, int n_in,
                              void* d_out, int out_size, void* d_ws, size_t ws_size,
                              hipStream_t stream)
{
  (void)in_sizes; (void)n_in; (void)out_size; (void)ws_size;
  const float* x      = (const float*)d_in[0];
  const float* w_qkv  = (const float*)d_in[1];
  const float* b_qkv  = (const float*)d_in[2];
  const float* w_proj = (const float*)d_in[3];
  const float* b_proj = (const float*)d_in[4];
  const float* q_g    = (const float*)d_in[5];
  const float* q_b    = (const float*)d_in[6];
  const float* k_g    = (const float*)d_in[7];
  const float* k_b    = (const float*)d_in[8];
  float* out = (float*)d_out;

  // workspace layout (~100.7 MB total)
  char* p = (char*)d_ws;
  unsigned short* x_bf  = (unsigned short*)p;  p += (size_t)4096 * 1024 * 2;
  unsigned short* wq_bf = (unsigned short*)p;  p += (size_t)3072 * 1024 * 2;
  unsigned short* wp_bf = (unsigned short*)p;  p += (size_t)1024 * 1024 * 2;
  float*          qkv   = (float*)p;           p += (size_t)4096 * 3072 * 4;
  unsigned short* qh    = (unsigned short*)p;  p += (size_t)32 * 2048 * 64 * 2;
  unsigned short* kh    = (unsigned short*)p;  p += (size_t)32 * 2048 * 64 * 2;
  unsigned short* vh    = (unsigned short*)p;  p += (size_t)32 * 2048 * 64 * 2;
  unsigned short* ao    = (unsigned short*)p;  p += (size_t)4096 * 1024 * 2;

  k_cvt<<<4096, 256, 0, stream>>>(x,      x_bf,  1048576);
  k_cvt<<<3072, 256, 0, stream>>>(w_qkv,  wq_bf,  786432);
  k_cvt<<<1024, 256, 0, stream>>>(w_proj, wp_bf,  262144);

  k_gemm_nt<<<dim3(24, 32), 256, 0, stream>>>(x_bf, wq_bf, b_qkv, qkv, 4096, 3072, 1024);
  k_ln<<<16384, 256, 0, stream>>>(qkv, q_g, q_b, k_g, k_b, qh, kh, vh);
  k_attn<<<dim3(32, 32), 256, 0, stream>>>(qh, kh, vh, ao);
  k_gemm_nt<<<dim3(8, 32), 256, 0, stream>>>(ao, wp_bf, b_proj, out, 4096, 1024, 1024);
}